// Round 3
// 305.796 us; speedup vs baseline: 1.0088x; 1.0088x over previous
//
#include <hip/hip_runtime.h>

#define TT   512
#define DD   6
#define HD   32
#define CH   32          // x-staging chunk (timesteps)
#define EPSL 1e-5f
#define L2E  1.44269504f
#define L2E2 2.88539008f

typedef _Float16 half8 __attribute__((ext_vector_type(8)));
typedef __attribute__((ext_vector_type(4))) float f32x4;

#define MFMA_F16(a, b, c) __builtin_amdgcn_mfma_f32_16x16x32_f16((a), (b), (c), 0, 0, 0)

// ====================================================================
// R11 (2nd resubmit — rounds 1 and 2 both hit GPUAcquisitionTimeout; no
// measurement of this kernel exists yet).
// R10 -> R11: UPD split across wave PAIRS (r-split) to reach 2 waves/SIMD.
// Diagnosis: 1 wave/SIMD (Occupancy 11.6%), VALUBusy 48.5% -> ~580 stall
// cycles/step with nothing to fill them. The only split that adds waves
// without idle lanes or extra barriers: both waves of a pair run the
// IDENTICAL 8 MFMAs (C has all 4 r-rows per lane anyway; MFMA pipe is
// cheap), but each wave runs UPD — the expensive part, 7 trans + ~13 VALU
// per r — for only 2 of the 4 r slots and writes only its own h rows
// [4q+r]. Rings, skew, barriers, LDS layout unchanged. 512 threads/block,
// 8 waves = 2/SIMD, one L0-role + one L1-role wave per SIMD so stalls
// interleave with independent issue.
// ====================================================================
__global__ __launch_bounds__(512, 2) void lstm2_pipe(
    const float* __restrict__ x,      // (B,512,6)
    const float* __restrict__ W_ih0,  // (128,6)
    const float* __restrict__ W_hh0,  // (128,32)
    const float* __restrict__ b_ih0,
    const float* __restrict__ b_hh0,
    const float* __restrict__ W_ih1,  // (128,32)
    const float* __restrict__ W_hh1,  // (128,32)
    const float* __restrict__ b_ih1,
    const float* __restrict__ b_hh1,
    const float* __restrict__ gamma,
    const float* __restrict__ beta,
    float* __restrict__ out)          // (B,32)
{
    const int tid = threadIdx.x;
    const int w   = tid >> 6;
    const int L   = w >> 2;        // 0: layer-0 role, 1: layer-1 role
    const int uh  = (w >> 1) & 1;  // unit half
    const int bh  = w & 1;         // r-pair half: bh=0 -> UPD r=0,1; bh=1 -> r=2,3
    const int ln  = tid & 63;
    const int q   = ln >> 4;
    const int n   = ln & 15;
    const int u   = 16 * uh + n;
    const int b0  = blockIdx.x << 4;

    __shared__ __align__(16) _Float16 h0r[4][16][40];
    __shared__ __align__(16) _Float16 h1r[2][16][40];
    __shared__ __align__(16) _Float16 xs[2][CH][16][8];
    __shared__ float ln_s[16][33];

    {   // zero rings and xs pads
        unsigned* p0 = (unsigned*)&h0r[0][0][0];
        for (int i = tid; i < (int)(sizeof(h0r) / 4); i += 512) p0[i] = 0u;
        unsigned* p1 = (unsigned*)&h1r[0][0][0];
        for (int i = tid; i < (int)(sizeof(h1r) / 4); i += 512) p1[i] = 0u;
        unsigned* p2 = (unsigned*)&xs[0][0][0][0];
        for (int i = tid; i < (int)(sizeof(xs) / 4); i += 512) p2[i] = 0u;
    }
    __syncthreads();   // xs fully zeroed before the prologue XSTORE(0)

    // ---------------- weight B-frags (fp16, pre-scaled) ----------------
    const float* Wa = L ? W_ih1 : W_hh0;
    const float* bi = L ? b_ih1 : b_ih0;
    const float* bh_ = L ? b_hh1 : b_hh0;

#define SETUP(p, SC) \
    half8 Ba##p, Bb##p; float K##p; { \
        const int g = 32 * (p) + u; \
        const float4* r4 = (const float4*)(Wa + g * 32 + 8 * q); \
        float4 va = r4[0], vb = r4[1]; \
        Ba##p = half8{(_Float16)(SC * va.x), (_Float16)(SC * va.y), \
                      (_Float16)(SC * va.z), (_Float16)(SC * va.w), \
                      (_Float16)(SC * vb.x), (_Float16)(SC * vb.y), \
                      (_Float16)(SC * vb.z), (_Float16)(SC * vb.w)}; \
        Bb##p = half8{0, 0, 0, 0, 0, 0, 0, 0}; \
        if (L) { \
            const float4* s4 = (const float4*)(W_hh1 + g * 32 + 8 * q); \
            float4 sa = s4[0], sb = s4[1]; \
            Bb##p = half8{(_Float16)(SC * sa.x), (_Float16)(SC * sa.y), \
                          (_Float16)(SC * sa.z), (_Float16)(SC * sa.w), \
                          (_Float16)(SC * sb.x), (_Float16)(SC * sb.y), \
                          (_Float16)(SC * sb.z), (_Float16)(SC * sb.w)}; \
        } else if (q == 0) { \
            const float* xw = W_ih0 + g * 6; \
            Bb##p[0] = (_Float16)(SC * xw[0]); Bb##p[1] = (_Float16)(SC * xw[1]); \
            Bb##p[2] = (_Float16)(SC * xw[2]); Bb##p[3] = (_Float16)(SC * xw[3]); \
            Bb##p[4] = (_Float16)(SC * xw[4]); Bb##p[5] = (_Float16)(SC * xw[5]); \
        } \
        K##p = __builtin_amdgcn_exp2f(SC * (bi[g] + bh_[g])); \
    }
    SETUP(0, -L2E) SETUP(1, -L2E) SETUP(2, -L2E2) SETUP(3, -L2E)
    const float K2c = L2E2 * K2;

    // ---------------- x chunk machinery (cooperative, all 512 threads) ----
    // 768 float4 per chunk: idx = tid for all threads, idx = tid+256 for the
    // upper half (L1-role waves carry the second slice).
    const int m0 = (tid       ) / 48, j0 = (tid       ) % 48;
    const int m1 = (tid + 256 ) / 48, j1 = (tid + 256 ) % 48;
    float4 xr0, xr1;

#define XLOAD(ch) { \
        const float* cb = x + (size_t)b0 * (TT * DD) + (ch) * (CH * DD); \
        xr0 = *(const float4*)(cb + (size_t)m0 * (TT * DD) + 4 * j0); \
        if (tid >= 256) xr1 = *(const float4*)(cb + (size_t)m1 * (TT * DD) + 4 * j1); }

#define XST1(mm, jj, v) { int f = 4 * (jj); \
          xb_[((f+0)/6)*128 + (mm)*8 + ((f+0)%6)] = (_Float16)v.x; \
          xb_[((f+1)/6)*128 + (mm)*8 + ((f+1)%6)] = (_Float16)v.y; \
          xb_[((f+2)/6)*128 + (mm)*8 + ((f+2)%6)] = (_Float16)v.z; \
          xb_[((f+3)/6)*128 + (mm)*8 + ((f+3)%6)] = (_Float16)v.w; }

#define XSTORE(buf) { \
        _Float16* xb_ = &xs[(buf)][0][0][0]; \
        XST1(m0, j0, xr0) \
        if (tid >= 256) { XST1(m1, j1, xr1) } }

    XLOAD(0)
    XSTORE(0)

    float cc0 = 0.f, cc1 = 0.f, cc2 = 0.f, cc3 = 0.f;   // c, PRE-SCALED by -2*log2e
    float hL0 = 0.f, hL1 = 0.f, hL2 = 0.f, hL3 = 0.f;   // fp32 h1 (LN epilogue)
    half8 AaN = {0,0,0,0,0,0,0,0};    // L1: prefetched h0 frag
    half8 AbN = {0,0,0,0,0,0,0,0};    // L0: prefetched x frag
    const f32x4 ZACC = {0.f, 0.f, 0.f, 0.f};

    __syncthreads();

    // initial x frag for s=0 (q>=1 lanes read x data their zero B-side ignores)
    AbN = *(const half8*)&xs[0][0][n][0];

    // reg-frag MFMA first (independent of the post-barrier ds_read)
#define GATE_L0(p) \
    f32x4 acc##p = MFMA_F16(AbN, Bb##p, ZACC); \
    acc##p = MFMA_F16(Aa, Ba##p, acc##p);
#define GATE_L1(p) \
    f32x4 acc##p = MFMA_F16(AaN, Ba##p, ZACC); \
    acc##p = MFMA_F16(Ab, Bb##p, acc##p);

    // rcp-merged update. A=K0*e0, F=K1*e1, B=K2*e2, O=K3*e3.
#define UPD(r, IS_L1, WS) { \
        float e0 = __builtin_amdgcn_exp2f(acc0[r]); \
        float e1 = __builtin_amdgcn_exp2f(acc1[r]); \
        float e2 = __builtin_amdgcn_exp2f(acc2[r]); \
        float e3 = __builtin_amdgcn_exp2f(acc3[r]); \
        float pA = fmaf(K0, e0, 1.0f); \
        float pF = fmaf(K1, e1, 1.0f); \
        float pB = fmaf(K2, e2, 1.0f); \
        float pO = fmaf(K3, e3, 1.0f); \
        float Qh = fmaf(K2c, e2, -L2E2); \
        float P  = pA * pB; \
        float R  = __builtin_amdgcn_rcpf(P * pF); \
        float nm = fmaf(cc##r, P, Qh * pF); \
        cc##r = nm * R; \
        float ec = __builtin_amdgcn_exp2f(cc##r); \
        float R2 = __builtin_amdgcn_rcpf(pO * (1.0f + ec)); \
        float h_ = (1.0f - ec) * R2; \
        if (IS_L1) { hL##r = h_; h1r[WS][4 * q + r][u] = (_Float16)h_; } \
        else       {             h0r[WS][4 * q + r][u] = (_Float16)h_; } }

    // Body J (s = s0+J), compile-time slots. ALL LDS reads (current frags
    // AND next-iter prefetches) issue at the TOP, unconditionally, so the
    // ~120cy latency hides under the 8 MFMAs + UPD that follow.
    // r-split: bh=0 wave updates r=0,1; bh=1 wave updates r=2,3 (disjoint
    // h-ring rows 4q+r, union covers the tile; MFMAs are duplicated).
#define BODY(J, S) { \
        if ((J) == 0 && ((S) & (CH - 1)) == 0 && (S) < TT - CH) { XLOAD(((S) >> 5) + 1) } \
        if (L) { \
            half8 Ab      = *(const half8*)&h1r[((J) + 1) & 1][n][8 * q]; \
            half8 AaN_nxt = *(const half8*)&h0r[((J) + 3) & 3][n][8 * q]; \
            if ((S) >= 2 && (S) < TT + 2) { \
                GATE_L1(0) GATE_L1(1) GATE_L1(2) GATE_L1(3) \
                if (bh == 0) { UPD(0, 1, (J) & 1) UPD(1, 1, (J) & 1) } \
                else         { UPD(2, 1, (J) & 1) UPD(3, 1, (J) & 1) } \
            } \
            AaN = AaN_nxt; \
        } else { \
            half8 Aa      = *(const half8*)&h0r[((J) + 3) & 3][n][8 * q]; \
            const int sn  = ((S) + 1 < TT) ? (S) + 1 : (S); \
            half8 AbN_nxt = *(const half8*)&xs[(sn >> 5) & 1][sn & (CH - 1)][n][0]; \
            if ((S) < TT) { \
                GATE_L0(0) GATE_L0(1) GATE_L0(2) GATE_L0(3) \
                if (bh == 0) { UPD(0, 0, (J) & 3) UPD(1, 0, (J) & 3) } \
                else         { UPD(2, 0, (J) & 3) UPD(3, 0, (J) & 3) } \
            } \
            AbN = AbN_nxt; \
        } \
        if ((J) == 2 && (((S) & (CH - 1)) == 30) && (S) < TT - 2) { XSTORE((((S) >> 5) + 1) & 1) } \
        __syncthreads(); }

    #pragma unroll 1
    for (int s0 = 0; s0 < 516; s0 += 4) {
        BODY(0, s0)
        BODY(1, s0 + 1)
        BODY(2, s0 + 2)
        BODY(3, s0 + 3)
    }

    // ---------------- LayerNorm epilogue ----------------
    if (L) {
        if (bh == 0) {
            ln_s[4 * q + 0][u] = hL0;
            ln_s[4 * q + 1][u] = hL1;
        } else {
            ln_s[4 * q + 2][u] = hL2;
            ln_s[4 * q + 3][u] = hL3;
        }
    }
    __syncthreads();

    if (tid < 16) {
        const int m = tid;
        float s = 0.f, s2 = 0.f;
        #pragma unroll
        for (int k = 0; k < HD; ++k) {
            float v = ln_s[m][k];
            s += v; s2 += v * v;
        }
        float mu  = s * (1.0f / HD);
        float var = s2 * (1.0f / HD) - mu * mu;
        float rr  = rsqrtf(var + EPSL);
        float* op = out + (size_t)(b0 + m) * HD;
        #pragma unroll
        for (int k = 0; k < HD; ++k)
            op[k] = (ln_s[m][k] - mu) * rr * gamma[k] + beta[k];
    }
}

extern "C" void kernel_launch(void* const* d_in, const int* in_sizes, int n_in,
                              void* d_out, int out_size, void* d_ws, size_t ws_size,
                              hipStream_t stream) {
    const float* x     = (const float*)d_in[0];
    const float* W_ih0 = (const float*)d_in[1];
    const float* W_hh0 = (const float*)d_in[2];
    const float* b_ih0 = (const float*)d_in[3];
    const float* b_hh0 = (const float*)d_in[4];
    const float* W_ih1 = (const float*)d_in[5];
    const float* W_hh1 = (const float*)d_in[6];
    const float* b_ih1 = (const float*)d_in[7];
    const float* b_hh1 = (const float*)d_in[8];
    const float* b_    = (const float*)d_in[9];
    const float* beta  = (const float*)d_in[10];
    float* out = (float*)d_out;

    const int B = in_sizes[0] / (TT * DD);   // 4096
    lstm2_pipe<<<B / 16, 512, 0, stream>>>(x, W_ih0, W_hh0, b_ih0, b_hh0,
                                           W_ih1, W_hh1, b_ih1, b_hh1,
                                           b_, beta, out);
}

// Round 4
// 304.251 us; speedup vs baseline: 1.0139x; 1.0051x over previous
//
#include <hip/hip_runtime.h>

#define TT   512
#define DD   6
#define HD   32
#define CH   32          // x-staging chunk (timesteps)
#define EPSL 1e-5f
#define L2E  1.44269504f
#define L2E2 2.88539008f

typedef _Float16 half8 __attribute__((ext_vector_type(8)));
typedef __attribute__((ext_vector_type(4))) float f32x4;

#define MFMA_F16(a, b, c) __builtin_amdgcn_mfma_f32_16x16x32_f16((a), (b), (c), 0, 0, 0)

// Raw barrier: only lgkmcnt(0) (h-ring ds_writes must be visible), NOT the
// compiler's full vmcnt(0)/expcnt(0) drain that __syncthreads emits. This
// keeps the 30-step XLOAD global prefetch in flight across barriers instead
// of stalling ~900cy on HBM at the first barrier after issue.
#define BAR() { asm volatile("s_waitcnt lgkmcnt(0)" ::: "memory"); \
                __builtin_amdgcn_s_barrier(); \
                asm volatile("" ::: "memory"); }

// ====================================================================
// R12 = R10 structure (4 waves — measured better than R11's 8) + two
// chain-cutters:
//  (1) raw s_barrier with manual lgkmcnt-only wait (see BAR above);
//  (2) wave-role ids via readfirstlane -> scalar branches instead of
//      exec-mask juggling (compiler can't prove tid>>6 is wave-uniform).
// R11 post-mortem: 2 waves/SIMD (r-split, dup MFMA) was NEUTRAL->worse
// (250 vs 243us; VALUBusy flat 46%): the step is loop-carried-chain-bound
// (write h -> barrier+drain -> ds_read h -> MFMA -> UPD trans chain ->
// write), not fillable-stall-bound. So: shorten the chain, don't add waves.
// ====================================================================
__global__ __launch_bounds__(256, 1) void lstm2_pipe(
    const float* __restrict__ x,      // (B,512,6)
    const float* __restrict__ W_ih0,  // (128,6)
    const float* __restrict__ W_hh0,  // (128,32)
    const float* __restrict__ b_ih0,
    const float* __restrict__ b_hh0,
    const float* __restrict__ W_ih1,  // (128,32)
    const float* __restrict__ W_hh1,  // (128,32)
    const float* __restrict__ b_ih1,
    const float* __restrict__ b_hh1,
    const float* __restrict__ gamma,
    const float* __restrict__ beta,
    float* __restrict__ out)          // (B,32)
{
    const int tid = threadIdx.x;
    const int w   = __builtin_amdgcn_readfirstlane(tid >> 6);  // wave id, SGPR
    const int L   = w >> 1;        // 0: layer-0 role, 1: layer-1 role (scalar)
    const int uh  = w & 1;         // unit half (scalar)
    const int ln  = tid & 63;
    const int q   = ln >> 4;
    const int n   = ln & 15;
    const int u   = 16 * uh + n;
    const int b0  = blockIdx.x << 4;

    __shared__ __align__(16) _Float16 h0r[4][16][40];
    __shared__ __align__(16) _Float16 h1r[2][16][40];
    __shared__ __align__(16) _Float16 xs[2][CH][16][8];
    __shared__ float ln_s[16][33];

    {   // zero rings and xs pads
        unsigned* p0 = (unsigned*)&h0r[0][0][0];
        for (int i = tid; i < (int)(sizeof(h0r) / 4); i += 256) p0[i] = 0u;
        unsigned* p1 = (unsigned*)&h1r[0][0][0];
        for (int i = tid; i < (int)(sizeof(h1r) / 4); i += 256) p1[i] = 0u;
        unsigned* p2 = (unsigned*)&xs[0][0][0][0];
        for (int i = tid; i < (int)(sizeof(xs) / 4); i += 256) p2[i] = 0u;
    }
    __syncthreads();   // xs fully zeroed before the prologue XSTORE(0)

    // ---------------- weight B-frags (fp16, pre-scaled) ----------------
    const float* Wa = L ? W_ih1 : W_hh0;
    const float* bi = L ? b_ih1 : b_ih0;
    const float* bh = L ? b_hh1 : b_hh0;

#define SETUP(p, SC) \
    half8 Ba##p, Bb##p; float K##p; { \
        const int g = 32 * (p) + u; \
        const float4* r4 = (const float4*)(Wa + g * 32 + 8 * q); \
        float4 va = r4[0], vb = r4[1]; \
        Ba##p = half8{(_Float16)(SC * va.x), (_Float16)(SC * va.y), \
                      (_Float16)(SC * va.z), (_Float16)(SC * va.w), \
                      (_Float16)(SC * vb.x), (_Float16)(SC * vb.y), \
                      (_Float16)(SC * vb.z), (_Float16)(SC * vb.w)}; \
        Bb##p = half8{0, 0, 0, 0, 0, 0, 0, 0}; \
        if (L) { \
            const float4* s4 = (const float4*)(W_hh1 + g * 32 + 8 * q); \
            float4 sa = s4[0], sb = s4[1]; \
            Bb##p = half8{(_Float16)(SC * sa.x), (_Float16)(SC * sa.y), \
                          (_Float16)(SC * sa.z), (_Float16)(SC * sa.w), \
                          (_Float16)(SC * sb.x), (_Float16)(SC * sb.y), \
                          (_Float16)(SC * sb.z), (_Float16)(SC * sb.w)}; \
        } else if (q == 0) { \
            const float* xw = W_ih0 + g * 6; \
            Bb##p[0] = (_Float16)(SC * xw[0]); Bb##p[1] = (_Float16)(SC * xw[1]); \
            Bb##p[2] = (_Float16)(SC * xw[2]); Bb##p[3] = (_Float16)(SC * xw[3]); \
            Bb##p[4] = (_Float16)(SC * xw[4]); Bb##p[5] = (_Float16)(SC * xw[5]); \
        } \
        K##p = __builtin_amdgcn_exp2f(SC * (bi[g] + bh[g])); \
    }
    SETUP(0, -L2E) SETUP(1, -L2E) SETUP(2, -L2E2) SETUP(3, -L2E)
    const float K2c = L2E2 * K2;

    // ---------------- x chunk machinery (cooperative, all 256 threads) ----
    const int m0 = (tid       ) / 48, j0 = (tid       ) % 48;
    const int m1 = (tid + 256 ) / 48, j1 = (tid + 256 ) % 48;
    const int m2 = (tid + 512 ) / 48, j2 = (tid + 512 ) % 48;
    float4 xr0, xr1, xr2;

#define XLOAD(ch) { \
        const float* cb = x + (size_t)b0 * (TT * DD) + (ch) * (CH * DD); \
        xr0 = *(const float4*)(cb + (size_t)m0 * (TT * DD) + 4 * j0); \
        xr1 = *(const float4*)(cb + (size_t)m1 * (TT * DD) + 4 * j1); \
        xr2 = *(const float4*)(cb + (size_t)m2 * (TT * DD) + 4 * j2); }

#define XSTORE(buf) { \
        _Float16* xb_ = &xs[(buf)][0][0][0]; \
        { int f = 4 * j0; float4 v = xr0; \
          xb_[((f+0)/6)*128 + m0*8 + ((f+0)%6)] = (_Float16)v.x; \
          xb_[((f+1)/6)*128 + m0*8 + ((f+1)%6)] = (_Float16)v.y; \
          xb_[((f+2)/6)*128 + m0*8 + ((f+2)%6)] = (_Float16)v.z; \
          xb_[((f+3)/6)*128 + m0*8 + ((f+3)%6)] = (_Float16)v.w; } \
        { int f = 4 * j1; float4 v = xr1; \
          xb_[((f+0)/6)*128 + m1*8 + ((f+0)%6)] = (_Float16)v.x; \
          xb_[((f+1)/6)*128 + m1*8 + ((f+1)%6)] = (_Float16)v.y; \
          xb_[((f+2)/6)*128 + m1*8 + ((f+2)%6)] = (_Float16)v.z; \
          xb_[((f+3)/6)*128 + m1*8 + ((f+3)%6)] = (_Float16)v.w; } \
        { int f = 4 * j2; float4 v = xr2; \
          xb_[((f+0)/6)*128 + m2*8 + ((f+0)%6)] = (_Float16)v.x; \
          xb_[((f+1)/6)*128 + m2*8 + ((f+1)%6)] = (_Float16)v.y; \
          xb_[((f+2)/6)*128 + m2*8 + ((f+2)%6)] = (_Float16)v.z; \
          xb_[((f+3)/6)*128 + m2*8 + ((f+3)%6)] = (_Float16)v.w; } }

    XLOAD(0)
    XSTORE(0)

    float cc0 = 0.f, cc1 = 0.f, cc2 = 0.f, cc3 = 0.f;   // c, PRE-SCALED by -2*log2e
    float hL0 = 0.f, hL1 = 0.f, hL2 = 0.f, hL3 = 0.f;   // fp32 h1 (LN epilogue)
    half8 AaN = {0,0,0,0,0,0,0,0};    // L1: prefetched h0 frag
    half8 AbN = {0,0,0,0,0,0,0,0};    // L0: prefetched x frag
    const f32x4 ZACC = {0.f, 0.f, 0.f, 0.f};

    __syncthreads();

    // initial x frag for s=0 (q>=1 lanes read x data their zero B-side ignores)
    AbN = *(const half8*)&xs[0][0][n][0];

    // reg-frag MFMA first (independent of the post-barrier ds_read)
#define GATE_L0(p) \
    f32x4 acc##p = MFMA_F16(AbN, Bb##p, ZACC); \
    acc##p = MFMA_F16(Aa, Ba##p, acc##p);
#define GATE_L1(p) \
    f32x4 acc##p = MFMA_F16(AaN, Ba##p, ZACC); \
    acc##p = MFMA_F16(Ab, Bb##p, acc##p);

    // rcp-merged update. A=K0*e0, F=K1*e1, B=K2*e2, O=K3*e3.
#define UPD(r, IS_L1, WS) { \
        float e0 = __builtin_amdgcn_exp2f(acc0[r]); \
        float e1 = __builtin_amdgcn_exp2f(acc1[r]); \
        float e2 = __builtin_amdgcn_exp2f(acc2[r]); \
        float e3 = __builtin_amdgcn_exp2f(acc3[r]); \
        float pA = fmaf(K0, e0, 1.0f); \
        float pF = fmaf(K1, e1, 1.0f); \
        float pB = fmaf(K2, e2, 1.0f); \
        float pO = fmaf(K3, e3, 1.0f); \
        float Qh = fmaf(K2c, e2, -L2E2); \
        float P  = pA * pB; \
        float R  = __builtin_amdgcn_rcpf(P * pF); \
        float nm = fmaf(cc##r, P, Qh * pF); \
        cc##r = nm * R; \
        float ec = __builtin_amdgcn_exp2f(cc##r); \
        float R2 = __builtin_amdgcn_rcpf(pO * (1.0f + ec)); \
        float h_ = (1.0f - ec) * R2; \
        if (IS_L1) { hL##r = h_; h1r[WS][4 * q + r][u] = (_Float16)h_; } \
        else       {             h0r[WS][4 * q + r][u] = (_Float16)h_; } }

    // Body J (s = s0+J), compile-time slots. ALL LDS reads (current frags
    // AND next-iter prefetches) issue at the TOP, unconditionally, so the
    // ~120cy latency hides under the 8 MFMAs + ~340cy UPD that follow.
#define BODY(J, S) { \
        if ((J) == 0 && ((S) & (CH - 1)) == 0 && (S) < TT - CH) { XLOAD(((S) >> 5) + 1) } \
        if (L) { \
            half8 Ab      = *(const half8*)&h1r[((J) + 1) & 1][n][8 * q]; \
            half8 AaN_nxt = *(const half8*)&h0r[((J) + 3) & 3][n][8 * q]; \
            if ((S) >= 2 && (S) < TT + 2) { \
                GATE_L1(0) GATE_L1(1) GATE_L1(2) GATE_L1(3) \
                UPD(0, 1, (J) & 1) UPD(1, 1, (J) & 1) \
                UPD(2, 1, (J) & 1) UPD(3, 1, (J) & 1) \
            } \
            AaN = AaN_nxt; \
        } else { \
            half8 Aa      = *(const half8*)&h0r[((J) + 3) & 3][n][8 * q]; \
            const int sn  = ((S) + 1 < TT) ? (S) + 1 : (S); \
            half8 AbN_nxt = *(const half8*)&xs[(sn >> 5) & 1][sn & (CH - 1)][n][0]; \
            if ((S) < TT) { \
                GATE_L0(0) GATE_L0(1) GATE_L0(2) GATE_L0(3) \
                UPD(0, 0, (J) & 3) UPD(1, 0, (J) & 3) \
                UPD(2, 0, (J) & 3) UPD(3, 0, (J) & 3) \
            } \
            AbN = AbN_nxt; \
        } \
        if ((J) == 2 && (((S) & (CH - 1)) == 30) && (S) < TT - 2) { XSTORE((((S) >> 5) + 1) & 1) } \
        BAR() }

    #pragma unroll 1
    for (int s0 = 0; s0 < 516; s0 += 4) {
        BODY(0, s0)
        BODY(1, s0 + 1)
        BODY(2, s0 + 2)
        BODY(3, s0 + 3)
    }

    // ---------------- LayerNorm epilogue ----------------
    if (L) {
        ln_s[4 * q + 0][u] = hL0;
        ln_s[4 * q + 1][u] = hL1;
        ln_s[4 * q + 2][u] = hL2;
        ln_s[4 * q + 3][u] = hL3;
    }
    __syncthreads();

    if (tid < 16) {
        const int m = tid;
        float s = 0.f, s2 = 0.f;
        #pragma unroll
        for (int k = 0; k < HD; ++k) {
            float v = ln_s[m][k];
            s += v; s2 += v * v;
        }
        float mu  = s * (1.0f / HD);
        float var = s2 * (1.0f / HD) - mu * mu;
        float rr  = rsqrtf(var + EPSL);
        float* op = out + (size_t)(b0 + m) * HD;
        #pragma unroll
        for (int k = 0; k < HD; ++k)
            op[k] = (ln_s[m][k] - mu) * rr * gamma[k] + beta[k];
    }
}

extern "C" void kernel_launch(void* const* d_in, const int* in_sizes, int n_in,
                              void* d_out, int out_size, void* d_ws, size_t ws_size,
                              hipStream_t stream) {
    const float* x     = (const float*)d_in[0];
    const float* W_ih0 = (const float*)d_in[1];
    const float* W_hh0 = (const float*)d_in[2];
    const float* b_ih0 = (const float*)d_in[3];
    const float* b_hh0 = (const float*)d_in[4];
    const float* W_ih1 = (const float*)d_in[5];
    const float* W_hh1 = (const float*)d_in[6];
    const float* b_ih1 = (const float*)d_in[7];
    const float* b_hh1 = (const float*)d_in[8];
    const float* gamma = (const float*)d_in[9];
    const float* beta  = (const float*)d_in[10];
    float* out = (float*)d_out;

    const int B = in_sizes[0] / (TT * DD);   // 4096
    lstm2_pipe<<<B / 16, 256, 0, stream>>>(x, W_ih0, W_hh0, b_ih0, b_hh0,
                                           W_ih1, W_hh1, b_ih1, b_hh1,
                                           gamma, beta, out);
}